// Round 4
// baseline (105.895 us; speedup 1.0000x reference)
//
#include <hip/hip_runtime.h>

#define NG 33               // gradient grid 33x33
#define HP 64               // perlin grid 64x64
#define HOUT 56
#define WOUT 56
#define NPIX (HOUT*WOUT)    // 3136
#define PLANE4 (768*784)    // float4s per (batch) image = 602112

typedef float f32x4 __attribute__((ext_vector_type(4)));

// ---------------- Kernel 1: perlin -> noise_mask / mask_out_b / lab_out ----
__global__ __launch_bounds__(256) void perlin_mask_kernel(
    const float* __restrict__ mask,     // (16,1,56,56)
    const float* __restrict__ labels,   // (16,1)
    const float* __restrict__ angles,   // (32,33,33)
    const float* __restrict__ chance,   // (32,)
    const int*   __restrict__ scale_x,  // (32,)
    const int*   __restrict__ scale_y,  // (32,)
    float* __restrict__ nm_ws,          // (32,3136) noise_mask
    float* __restrict__ out_maskb,      // (32,3136) as float 0/1
    float* __restrict__ out_lab)        // (32,)
{
    __shared__ double gx[NG*NG];
    __shared__ double gy[NG*NG];
    __shared__ double pn[HP*HP];
    __shared__ int anyflag;

    const int b2  = blockIdx.x;   // 0..31
    const int tid = threadIdx.x;
    if (tid == 0) anyflag = 0;

    // gradients in double for accuracy
    for (int t = tid; t < NG*NG; t += 256) {
        double a = (double)angles[b2*NG*NG + t];
        gx[t] = cos(a);
        gy[t] = sin(a);
    }
    __syncthreads();

    const int sx = 1 << scale_x[b2];
    const int sy = 1 << scale_y[b2];

    // 64x64 perlin grid
    for (int t = tid; t < HP*HP; t += 256) {
        int i = t >> 6, j = t & 63;
        int ix = i * sx, jy = j * sy;
        int c0 = ix >> 6, c1 = jy >> 6;
        double fu = (double)(ix & 63) * (1.0/64.0);
        double fv = (double)(jy & 63) * (1.0/64.0);
        int i00 = c0*NG + c1;
        double n00 = fu       * gx[i00]      + fv       * gy[i00];
        double n10 = (fu-1.0) * gx[i00+NG]   + fv       * gy[i00+NG];
        double n01 = fu       * gx[i00+1]    + (fv-1.0) * gy[i00+1];
        double n11 = (fu-1.0) * gx[i00+NG+1] + (fv-1.0) * gy[i00+NG+1];
        double tu = fu*fu*fu*(fu*(fu*6.0-15.0)+10.0);
        double tv = fv*fv*fv*(fv*(fv*6.0-15.0)+10.0);
        double l0 = n00 + tu*(n10-n00);
        double l1 = n01 + tu*(n11-n01);
        pn[t] = 1.4142135623730951 * (l0 + tv*(l1-l0));
    }
    __syncthreads();

    const float ch  = chance[b2];
    const float lab = labels[b2 & 15];
    int myany = 0;

    for (int t = tid; t < NPIX; t += 256) {
        int h = t / WOUT, w = t - (t / WOUT) * WOUT;
        double py = (h + 0.5)*(64.0/56.0) - 0.5;
        py = fmin(fmax(py, 0.0), 63.0);
        double px = (w + 0.5)*(64.0/56.0) - 0.5;
        px = fmin(fmax(px, 0.0), 63.0);
        int y0 = (int)floor(py), x0 = (int)floor(px);
        int y1 = min(y0+1, 63),  x1 = min(x0+1, 63);
        double wy = py - (double)y0, wx = px - (double)x0;
        double v00 = pn[y0*64+x0], v01 = pn[y0*64+x1];
        double v10 = pn[y1*64+x0], v11 = pn[y1*64+x1];
        double top = v00*(1.0-wx) + v01*wx;
        double bot = v10*(1.0-wx) + v11*wx;
        double val = top*(1.0-wy) + bot*wy;

        float thr = (val > 0.5) ? 1.0f : 0.0f;
        if (ch > 0.5f) thr = 0.0f;

        float mv  = mask[(b2 & 15)*NPIX + t];
        float nm  = (1.0f - lab) * (1.0f - mv) * thr;
        float mout = mv + nm;
        float mob  = (mout > 0.0f) ? 1.0f : 0.0f;
        myany |= (mob > 0.0f) ? 1 : 0;

        nm_ws[b2*NPIX + t]     = nm;
        out_maskb[b2*NPIX + t] = mob;
    }

    if (myany) atomicOr(&anyflag, 1);
    __syncthreads();
    if (tid == 0) {
        float na = anyflag ? 1.0f : 0.0f;
        out_lab[b2] = (lab + na > 0.0f) ? 1.0f : 0.0f;
    }
}

// ---------------- Kernel 2: perturbed = input2 + noise * noise_mask --------
// Each thread handles TWO float4s (at base and base+256) for BOTH concat
// halves b and b+16: input fetched once, noise fetched only where the mask
// float4 is nonzero (exec-masked loads skip HBM lines for zero regions).
// 2x per-thread work doubles outstanding loads per wave (MLP) to push the
// mixed read/write stream closer to the ~6.3 TB/s copy ceiling.
__global__ __launch_bounds__(256) void perturb_kernel(
    const f32x4* __restrict__ input,    // (16, 768, 784) float4
    const f32x4* __restrict__ noise,    // (32, 768, 784) float4
    const f32x4* __restrict__ nm_ws,    // (32, 784) float4
    f32x4* __restrict__ out)            // (32, 768, 784) float4
{
    const int b    = blockIdx.y;                        // 0..15
    const int rem0 = blockIdx.x * 512 + threadIdx.x;    // first float4
    const int rem1 = rem0 + 256;                        // second float4
    const int p40  = rem0 % 784;
    const int p41  = rem1 % 784;
    const int iA0  = b * PLANE4 + rem0;
    const int iA1  = b * PLANE4 + rem1;
    const int iB0  = iA0 + 16 * PLANE4;
    const int iB1  = iA1 + 16 * PLANE4;

    f32x4 in0 = __builtin_nontemporal_load(&input[iA0]);
    f32x4 in1 = __builtin_nontemporal_load(&input[iA1]);
    f32x4 ma0 = nm_ws[b * 784 + p40];
    f32x4 ma1 = nm_ws[b * 784 + p41];
    f32x4 mb0 = nm_ws[(b + 16) * 784 + p40];
    f32x4 mb1 = nm_ws[(b + 16) * 784 + p41];

    f32x4 oa0 = in0, oa1 = in1;
    f32x4 ob0 = in0, ob1 = in1;

    if (ma0.x + ma0.y + ma0.z + ma0.w > 0.0f) {
        f32x4 n = __builtin_nontemporal_load(&noise[iA0]);
        oa0 = in0 + n * ma0;
    }
    if (ma1.x + ma1.y + ma1.z + ma1.w > 0.0f) {
        f32x4 n = __builtin_nontemporal_load(&noise[iA1]);
        oa1 = in1 + n * ma1;
    }
    if (mb0.x + mb0.y + mb0.z + mb0.w > 0.0f) {
        f32x4 n = __builtin_nontemporal_load(&noise[iB0]);
        ob0 = in0 + n * mb0;
    }
    if (mb1.x + mb1.y + mb1.z + mb1.w > 0.0f) {
        f32x4 n = __builtin_nontemporal_load(&noise[iB1]);
        ob1 = in1 + n * mb1;
    }

    __builtin_nontemporal_store(oa0, &out[iA0]);
    __builtin_nontemporal_store(oa1, &out[iA1]);
    __builtin_nontemporal_store(ob0, &out[iB0]);
    __builtin_nontemporal_store(ob1, &out[iB1]);
}

extern "C" void kernel_launch(void* const* d_in, const int* in_sizes, int n_in,
                              void* d_out, int out_size, void* d_ws, size_t ws_size,
                              hipStream_t stream) {
    const float* input   = (const float*)d_in[0];
    const float* mask    = (const float*)d_in[1];
    const float* labels  = (const float*)d_in[2];
    const float* noise   = (const float*)d_in[3];
    const float* angles  = (const float*)d_in[4];
    const float* chance  = (const float*)d_in[5];
    const int*   scale_x = (const int*)d_in[6];
    const int*   scale_y = (const int*)d_in[7];

    float* out   = (float*)d_out;
    float* nm_ws = (float*)d_ws;                    // 32*3136 floats = 401 KB

    const long long OFF1 = 32LL * 768 * 3136;       // perturbed elements
    const long long OFF2 = OFF1 + 32LL * 3136;      // + mask_out_b elements

    perlin_mask_kernel<<<32, 256, 0, stream>>>(
        mask, labels, angles, chance, scale_x, scale_y,
        nm_ws, out + OFF1, out + OFF2);

    dim3 grid(PLANE4 / 512, 16, 1);                 // 1176 x 16 blocks
    perturb_kernel<<<grid, 256, 0, stream>>>(
        (const f32x4*)input, (const f32x4*)noise,
        (const f32x4*)nm_ws, (f32x4*)out);
}

// Round 5
// 97.453 us; speedup vs baseline: 1.0866x; 1.0866x over previous
//
#include <hip/hip_runtime.h>

#define NG 33               // gradient grid 33x33
#define HP 64               // perlin grid 64x64
#define HOUT 56
#define WOUT 56
#define NPIX (HOUT*WOUT)    // 3136
#define PLANE4 (768*784)    // float4s per (batch) image = 602112

typedef float f32x4 __attribute__((ext_vector_type(4)));

// ---------------- Kernel 1: perlin -> noise_mask / mask_out_b / lab_out ----
__global__ __launch_bounds__(256) void perlin_mask_kernel(
    const float* __restrict__ mask,     // (16,1,56,56)
    const float* __restrict__ labels,   // (16,1)
    const float* __restrict__ angles,   // (32,33,33)
    const float* __restrict__ chance,   // (32,)
    const int*   __restrict__ scale_x,  // (32,)
    const int*   __restrict__ scale_y,  // (32,)
    float* __restrict__ nm_ws,          // (32,3136) noise_mask
    float* __restrict__ out_maskb,      // (32,3136) as float 0/1
    float* __restrict__ out_lab)        // (32,)
{
    __shared__ double gx[NG*NG];
    __shared__ double gy[NG*NG];
    __shared__ double pn[HP*HP];
    __shared__ int anyflag;

    const int b2  = blockIdx.x;   // 0..31
    const int tid = threadIdx.x;
    if (tid == 0) anyflag = 0;

    // gradients in double for accuracy
    for (int t = tid; t < NG*NG; t += 256) {
        double a = (double)angles[b2*NG*NG + t];
        gx[t] = cos(a);
        gy[t] = sin(a);
    }
    __syncthreads();

    const int sx = 1 << scale_x[b2];
    const int sy = 1 << scale_y[b2];

    // 64x64 perlin grid
    for (int t = tid; t < HP*HP; t += 256) {
        int i = t >> 6, j = t & 63;
        int ix = i * sx, jy = j * sy;
        int c0 = ix >> 6, c1 = jy >> 6;
        double fu = (double)(ix & 63) * (1.0/64.0);
        double fv = (double)(jy & 63) * (1.0/64.0);
        int i00 = c0*NG + c1;
        double n00 = fu       * gx[i00]      + fv       * gy[i00];
        double n10 = (fu-1.0) * gx[i00+NG]   + fv       * gy[i00+NG];
        double n01 = fu       * gx[i00+1]    + (fv-1.0) * gy[i00+1];
        double n11 = (fu-1.0) * gx[i00+NG+1] + (fv-1.0) * gy[i00+NG+1];
        double tu = fu*fu*fu*(fu*(fu*6.0-15.0)+10.0);
        double tv = fv*fv*fv*(fv*(fv*6.0-15.0)+10.0);
        double l0 = n00 + tu*(n10-n00);
        double l1 = n01 + tu*(n11-n01);
        pn[t] = 1.4142135623730951 * (l0 + tv*(l1-l0));
    }
    __syncthreads();

    const float ch  = chance[b2];
    const float lab = labels[b2 & 15];
    int myany = 0;

    for (int t = tid; t < NPIX; t += 256) {
        int h = t / WOUT, w = t - (t / WOUT) * WOUT;
        double py = (h + 0.5)*(64.0/56.0) - 0.5;
        py = fmin(fmax(py, 0.0), 63.0);
        double px = (w + 0.5)*(64.0/56.0) - 0.5;
        px = fmin(fmax(px, 0.0), 63.0);
        int y0 = (int)floor(py), x0 = (int)floor(px);
        int y1 = min(y0+1, 63),  x1 = min(x0+1, 63);
        double wy = py - (double)y0, wx = px - (double)x0;
        double v00 = pn[y0*64+x0], v01 = pn[y0*64+x1];
        double v10 = pn[y1*64+x0], v11 = pn[y1*64+x1];
        double top = v00*(1.0-wx) + v01*wx;
        double bot = v10*(1.0-wx) + v11*wx;
        double val = top*(1.0-wy) + bot*wy;

        float thr = (val > 0.5) ? 1.0f : 0.0f;
        if (ch > 0.5f) thr = 0.0f;

        float mv  = mask[(b2 & 15)*NPIX + t];
        float nm  = (1.0f - lab) * (1.0f - mv) * thr;
        float mout = mv + nm;
        float mob  = (mout > 0.0f) ? 1.0f : 0.0f;
        myany |= (mob > 0.0f) ? 1 : 0;

        nm_ws[b2*NPIX + t]     = nm;
        out_maskb[b2*NPIX + t] = mob;
    }

    if (myany) atomicOr(&anyflag, 1);
    __syncthreads();
    if (tid == 0) {
        float na = anyflag ? 1.0f : 0.0f;
        out_lab[b2] = (lab + na > 0.0f) ? 1.0f : 0.0f;
    }
}

// ---------------- Kernel 2: perturbed = input2 + noise * noise_mask --------
// Each thread handles TWO float4s (at base and base+256, both wave-coalesced)
// for BOTH concat halves b and b+16: input fetched once, noise fetched only
// where the mask float4 is nonzero (exec-masked loads skip HBM lines for zero
// regions). Plain (cached) loads — round-4 A/B showed nontemporal LOADS
// regress; NT is kept on stores only (streamed output, never re-read).
__global__ __launch_bounds__(256) void perturb_kernel(
    const f32x4* __restrict__ input,    // (16, 768, 784) float4
    const f32x4* __restrict__ noise,    // (32, 768, 784) float4
    const f32x4* __restrict__ nm_ws,    // (32, 784) float4
    f32x4* __restrict__ out)            // (32, 768, 784) float4
{
    const int b    = blockIdx.y;                        // 0..15
    const int rem0 = blockIdx.x * 512 + threadIdx.x;    // first float4
    const int rem1 = rem0 + 256;                        // second float4
    const int p40  = rem0 % 784;
    const int p41  = rem1 % 784;
    const int iA0  = b * PLANE4 + rem0;
    const int iA1  = b * PLANE4 + rem1;
    const int iB0  = iA0 + 16 * PLANE4;
    const int iB1  = iA1 + 16 * PLANE4;

    f32x4 in0 = input[iA0];
    f32x4 in1 = input[iA1];
    f32x4 ma0 = nm_ws[b * 784 + p40];
    f32x4 ma1 = nm_ws[b * 784 + p41];
    f32x4 mb0 = nm_ws[(b + 16) * 784 + p40];
    f32x4 mb1 = nm_ws[(b + 16) * 784 + p41];

    f32x4 oa0 = in0, oa1 = in1;
    f32x4 ob0 = in0, ob1 = in1;

    if (ma0.x + ma0.y + ma0.z + ma0.w > 0.0f) {
        f32x4 n = noise[iA0];
        oa0 = in0 + n * ma0;
    }
    if (ma1.x + ma1.y + ma1.z + ma1.w > 0.0f) {
        f32x4 n = noise[iA1];
        oa1 = in1 + n * ma1;
    }
    if (mb0.x + mb0.y + mb0.z + mb0.w > 0.0f) {
        f32x4 n = noise[iB0];
        ob0 = in0 + n * mb0;
    }
    if (mb1.x + mb1.y + mb1.z + mb1.w > 0.0f) {
        f32x4 n = noise[iB1];
        ob1 = in1 + n * mb1;
    }

    __builtin_nontemporal_store(oa0, &out[iA0]);
    __builtin_nontemporal_store(oa1, &out[iA1]);
    __builtin_nontemporal_store(ob0, &out[iB0]);
    __builtin_nontemporal_store(ob1, &out[iB1]);
}

extern "C" void kernel_launch(void* const* d_in, const int* in_sizes, int n_in,
                              void* d_out, int out_size, void* d_ws, size_t ws_size,
                              hipStream_t stream) {
    const float* input   = (const float*)d_in[0];
    const float* mask    = (const float*)d_in[1];
    const float* labels  = (const float*)d_in[2];
    const float* noise   = (const float*)d_in[3];
    const float* angles  = (const float*)d_in[4];
    const float* chance  = (const float*)d_in[5];
    const int*   scale_x = (const int*)d_in[6];
    const int*   scale_y = (const int*)d_in[7];

    float* out   = (float*)d_out;
    float* nm_ws = (float*)d_ws;                    // 32*3136 floats = 401 KB

    const long long OFF1 = 32LL * 768 * 3136;       // perturbed elements
    const long long OFF2 = OFF1 + 32LL * 3136;      // + mask_out_b elements

    perlin_mask_kernel<<<32, 256, 0, stream>>>(
        mask, labels, angles, chance, scale_x, scale_y,
        nm_ws, out + OFF1, out + OFF2);

    dim3 grid(PLANE4 / 512, 16, 1);                 // 1176 x 16 blocks
    perturb_kernel<<<grid, 256, 0, stream>>>(
        (const f32x4*)input, (const f32x4*)noise,
        (const f32x4*)nm_ws, (f32x4*)out);
}

// Round 6
// 89.855 us; speedup vs baseline: 1.1785x; 1.0846x over previous
//
#include <hip/hip_runtime.h>

#define NG 33               // gradient grid 33x33
#define HP 64               // perlin grid 64x64
#define HOUT 56
#define WOUT 56
#define NPIX (HOUT*WOUT)    // 3136
#define PLANE4 (768*784)    // float4s per (batch) image = 602112

typedef float f32x4 __attribute__((ext_vector_type(4)));

// ---------------- Kernel 1: perlin -> noise_mask / mask_out_b / lab_out ----
// 1024 threads/block: 1 double-sincos per thread (1089 gradients), 4 perlin
// grid points per thread, ~3 output pixels per thread. k1 is a serial tail
// ahead of the dependent k2 (only 32 blocks) — minimize its latency.
__global__ __launch_bounds__(1024) void perlin_mask_kernel(
    const float* __restrict__ mask,     // (16,1,56,56)
    const float* __restrict__ labels,   // (16,1)
    const float* __restrict__ angles,   // (32,33,33)
    const float* __restrict__ chance,   // (32,)
    const int*   __restrict__ scale_x,  // (32,)
    const int*   __restrict__ scale_y,  // (32,)
    float* __restrict__ nm_ws,          // (32,3136) noise_mask
    float* __restrict__ out_maskb,      // (32,3136) as float 0/1
    float* __restrict__ out_lab)        // (32,)
{
    __shared__ double gx[NG*NG];
    __shared__ double gy[NG*NG];
    __shared__ double pn[HP*HP];
    __shared__ int anyflag;

    const int b2  = blockIdx.x;   // 0..31
    const int tid = threadIdx.x;
    if (tid == 0) anyflag = 0;

    // gradients in double for accuracy; sincos halves transcendental cost
    if (tid < NG*NG) {
        double a = (double)angles[b2*NG*NG + tid];
        double s, c;
        sincos(a, &s, &c);
        gx[tid] = c;
        gy[tid] = s;
    }
    __syncthreads();

    const int sx = 1 << scale_x[b2];
    const int sy = 1 << scale_y[b2];

    // 64x64 perlin grid: 4 points per thread
    #pragma unroll
    for (int t = tid; t < HP*HP; t += 1024) {
        int i = t >> 6, j = t & 63;
        int ix = i * sx, jy = j * sy;
        int c0 = ix >> 6, c1 = jy >> 6;
        double fu = (double)(ix & 63) * (1.0/64.0);
        double fv = (double)(jy & 63) * (1.0/64.0);
        int i00 = c0*NG + c1;
        double n00 = fu       * gx[i00]      + fv       * gy[i00];
        double n10 = (fu-1.0) * gx[i00+NG]   + fv       * gy[i00+NG];
        double n01 = fu       * gx[i00+1]    + (fv-1.0) * gy[i00+1];
        double n11 = (fu-1.0) * gx[i00+NG+1] + (fv-1.0) * gy[i00+NG+1];
        double tu = fu*fu*fu*(fu*(fu*6.0-15.0)+10.0);
        double tv = fv*fv*fv*(fv*(fv*6.0-15.0)+10.0);
        double l0 = n00 + tu*(n10-n00);
        double l1 = n01 + tu*(n11-n01);
        pn[t] = 1.4142135623730951 * (l0 + tv*(l1-l0));
    }
    __syncthreads();

    const float ch  = chance[b2];
    const float lab = labels[b2 & 15];
    int myany = 0;

    for (int t = tid; t < NPIX; t += 1024) {
        int h = t / WOUT, w = t - (t / WOUT) * WOUT;
        double py = (h + 0.5)*(64.0/56.0) - 0.5;
        py = fmin(fmax(py, 0.0), 63.0);
        double px = (w + 0.5)*(64.0/56.0) - 0.5;
        px = fmin(fmax(px, 0.0), 63.0);
        int y0 = (int)floor(py), x0 = (int)floor(px);
        int y1 = min(y0+1, 63),  x1 = min(x0+1, 63);
        double wy = py - (double)y0, wx = px - (double)x0;
        double v00 = pn[y0*64+x0], v01 = pn[y0*64+x1];
        double v10 = pn[y1*64+x0], v11 = pn[y1*64+x1];
        double top = v00*(1.0-wx) + v01*wx;
        double bot = v10*(1.0-wx) + v11*wx;
        double val = top*(1.0-wy) + bot*wy;

        float thr = (val > 0.5) ? 1.0f : 0.0f;
        if (ch > 0.5f) thr = 0.0f;

        float mv  = mask[(b2 & 15)*NPIX + t];
        float nm  = (1.0f - lab) * (1.0f - mv) * thr;
        float mout = mv + nm;
        float mob  = (mout > 0.0f) ? 1.0f : 0.0f;
        myany |= (mob > 0.0f) ? 1 : 0;

        nm_ws[b2*NPIX + t]     = nm;
        out_maskb[b2*NPIX + t] = mob;
    }

    if (myany) atomicOr(&anyflag, 1);
    __syncthreads();
    if (tid == 0) {
        float na = anyflag ? 1.0f : 0.0f;
        out_lab[b2] = (lab + na > 0.0f) ? 1.0f : 0.0f;
    }
}

// ---------------- Kernel 2: perturbed = input2 + noise * noise_mask --------
// Each thread handles TWO float4s (at base and base+256, both wave-coalesced)
// for BOTH concat halves b and b+16: input fetched once, noise fetched only
// where the mask float4 is nonzero (exec-masked loads skip HBM lines for zero
// regions). Plain (cached) loads — round-4 A/B showed nontemporal LOADS
// regress; NT is kept on stores only (streamed output, never re-read).
__global__ __launch_bounds__(256) void perturb_kernel(
    const f32x4* __restrict__ input,    // (16, 768, 784) float4
    const f32x4* __restrict__ noise,    // (32, 768, 784) float4
    const f32x4* __restrict__ nm_ws,    // (32, 784) float4
    f32x4* __restrict__ out)            // (32, 768, 784) float4
{
    const int b    = blockIdx.y;                        // 0..15
    const int rem0 = blockIdx.x * 512 + threadIdx.x;    // first float4
    const int rem1 = rem0 + 256;                        // second float4
    const int p40  = rem0 % 784;
    const int p41  = rem1 % 784;
    const int iA0  = b * PLANE4 + rem0;
    const int iA1  = b * PLANE4 + rem1;
    const int iB0  = iA0 + 16 * PLANE4;
    const int iB1  = iA1 + 16 * PLANE4;

    f32x4 in0 = input[iA0];
    f32x4 in1 = input[iA1];
    f32x4 ma0 = nm_ws[b * 784 + p40];
    f32x4 ma1 = nm_ws[b * 784 + p41];
    f32x4 mb0 = nm_ws[(b + 16) * 784 + p40];
    f32x4 mb1 = nm_ws[(b + 16) * 784 + p41];

    f32x4 oa0 = in0, oa1 = in1;
    f32x4 ob0 = in0, ob1 = in1;

    if (ma0.x + ma0.y + ma0.z + ma0.w > 0.0f) {
        f32x4 n = noise[iA0];
        oa0 = in0 + n * ma0;
    }
    if (ma1.x + ma1.y + ma1.z + ma1.w > 0.0f) {
        f32x4 n = noise[iA1];
        oa1 = in1 + n * ma1;
    }
    if (mb0.x + mb0.y + mb0.z + mb0.w > 0.0f) {
        f32x4 n = noise[iB0];
        ob0 = in0 + n * mb0;
    }
    if (mb1.x + mb1.y + mb1.z + mb1.w > 0.0f) {
        f32x4 n = noise[iB1];
        ob1 = in1 + n * mb1;
    }

    __builtin_nontemporal_store(oa0, &out[iA0]);
    __builtin_nontemporal_store(oa1, &out[iA1]);
    __builtin_nontemporal_store(ob0, &out[iB0]);
    __builtin_nontemporal_store(ob1, &out[iB1]);
}

extern "C" void kernel_launch(void* const* d_in, const int* in_sizes, int n_in,
                              void* d_out, int out_size, void* d_ws, size_t ws_size,
                              hipStream_t stream) {
    const float* input   = (const float*)d_in[0];
    const float* mask    = (const float*)d_in[1];
    const float* labels  = (const float*)d_in[2];
    const float* noise   = (const float*)d_in[3];
    const float* angles  = (const float*)d_in[4];
    const float* chance  = (const float*)d_in[5];
    const int*   scale_x = (const int*)d_in[6];
    const int*   scale_y = (const int*)d_in[7];

    float* out   = (float*)d_out;
    float* nm_ws = (float*)d_ws;                    // 32*3136 floats = 401 KB

    const long long OFF1 = 32LL * 768 * 3136;       // perturbed elements
    const long long OFF2 = OFF1 + 32LL * 3136;      // + mask_out_b elements

    perlin_mask_kernel<<<32, 1024, 0, stream>>>(
        mask, labels, angles, chance, scale_x, scale_y,
        nm_ws, out + OFF1, out + OFF2);

    dim3 grid(PLANE4 / 512, 16, 1);                 // 1176 x 16 blocks
    perturb_kernel<<<grid, 256, 0, stream>>>(
        (const f32x4*)input, (const f32x4*)noise,
        (const f32x4*)nm_ws, (f32x4*)out);
}